// Round 3
// baseline (903.631 us; speedup 1.0000x reference)
//
#include <hip/hip_runtime.h>
#include <cstdint>
#include <cstddef>

typedef unsigned short u16;
typedef __attribute__((ext_vector_type(8))) short short8;
typedef __attribute__((ext_vector_type(4))) float floatx4;

constexpr int D_ = 1024;
constexpr int B_ = 8;
constexpr int L_ = 4096;
constexpr int M_ = B_ * L_;        // 32768 tokens
constexpr int NCHUNK = 64;         // chunks along L
constexpr int CLEN = L_ / NCHUNK;  // 64 steps per chunk
constexpr float EPS_ = 1e-6f;

__device__ __forceinline__ float bf2f(u16 b) {
    union { unsigned u; float f; } x; x.u = ((unsigned)b) << 16; return x.f;
}
__device__ __forceinline__ u16 f2bf(float f) {
    union { float f; unsigned u; } x; x.f = f;
    unsigned r = x.u + 0x7fffu + ((x.u >> 16) & 1u);
    return (u16)(r >> 16);
}
__device__ __forceinline__ float sigmoidf_(float x) {
    return 1.f / (1.f + __expf(-x));
}

// convert 8 consecutive fp32 (two float4) to short8 of bf16
__device__ __forceinline__ short8 cvt8(const float* __restrict__ p) {
    float4 a = *(const float4*)p;
    float4 b = *(const float4*)(p + 4);
    short8 o;
    o[0] = (short)f2bf(a.x); o[1] = (short)f2bf(a.y);
    o[2] = (short)f2bf(a.z); o[3] = (short)f2bf(a.w);
    o[4] = (short)f2bf(b.x); o[5] = (short)f2bf(b.y);
    o[6] = (short)f2bf(b.z); o[7] = (short)f2bf(b.w);
    return o;
}

// ---------------- per-token inverse norm: inv = 1 / (||x||/sqrt(D) + eps) ----------------
__global__ __launch_bounds__(256) void rmsinv_kernel(const float* __restrict__ x,
                                                     float* __restrict__ inv) {
    const int row = blockIdx.x;
    const float* xr = x + (size_t)row * D_;
    const int t = threadIdx.x;
    float4 xv = *(const float4*)&xr[t * 4];
    float ss = xv.x * xv.x + xv.y * xv.y + xv.z * xv.z + xv.w * xv.w;
#pragma unroll
    for (int m = 32; m >= 1; m >>= 1) ss += __shfl_xor(ss, m, 64);
    __shared__ float red[4];
    const int wave = t >> 6, lane = t & 63;
    if (lane == 0) red[wave] = ss;
    __syncthreads();
    if (t == 0) {
        float tot = red[0] + red[1] + red[2] + red[3];
        inv[row] = 1.f / (sqrtf(tot * (1.f / D_)) + EPS_);
    }
}

// ---------------- GEMM1: 128x128 tile, RMSNorm fused into A staging ----------------
// A = bf16(x * inv_tok * scale); Bw = w_in [3072,1024] fp32 row-major (B^T layout).
// plane 0: g = sigmoid(.), plane 1: v = raw, plane 2: f = sigmoid(. - 1)
__global__ __launch_bounds__(256) void gemm1_kernel(const float* __restrict__ x,
                                                    const float* __restrict__ inv,
                                                    const float* __restrict__ scale,
                                                    const float* __restrict__ w_in,
                                                    u16* __restrict__ g_buf,
                                                    u16* __restrict__ v_buf,
                                                    u16* __restrict__ f_buf) {
    __shared__ __align__(16) u16 As[128 * 40];
    __shared__ __align__(16) u16 Bs[128 * 40];
    const int m0 = blockIdx.y * 128;
    const int n0 = blockIdx.x * 128;   // 0..2944; plane uniform per block
    const int t = threadIdx.x;
    const int wave = t >> 6, lane = t & 63;
    const int wm0 = (wave >> 1) * 64, wn0 = (wave & 1) * 64;
    const int l15 = lane & 15, quad = lane >> 4;

    floatx4 acc[4][4];
#pragma unroll
    for (int i = 0; i < 4; i++)
#pragma unroll
        for (int j = 0; j < 4; j++) { floatx4 z = {0.f, 0.f, 0.f, 0.f}; acc[i][j] = z; }

    for (int k0 = 0; k0 < 1024; k0 += 32) {
        __syncthreads();
#pragma unroll
        for (int i = 0; i < 2; i++) {
            int c = t + i * 256;             // 512 chunks of 8 elems per tile
            int row = c >> 2, col = (c & 3) * 8;
            // A: x * inv * scale, converted to bf16
            const float* xp = &x[(size_t)(m0 + row) * 1024 + k0 + col];
            float4 xa = *(const float4*)xp;
            float4 xb = *(const float4*)(xp + 4);
            float4 sa = *(const float4*)&scale[k0 + col];
            float4 sb = *(const float4*)&scale[k0 + col + 4];
            float iv = inv[m0 + row];
            short8 o;
            o[0] = (short)f2bf(xa.x * iv * sa.x);
            o[1] = (short)f2bf(xa.y * iv * sa.y);
            o[2] = (short)f2bf(xa.z * iv * sa.z);
            o[3] = (short)f2bf(xa.w * iv * sa.w);
            o[4] = (short)f2bf(xb.x * iv * sb.x);
            o[5] = (short)f2bf(xb.y * iv * sb.y);
            o[6] = (short)f2bf(xb.z * iv * sb.z);
            o[7] = (short)f2bf(xb.w * iv * sb.w);
            *(short8*)&As[row * 40 + col] = o;
            *(short8*)&Bs[row * 40 + col] =
                cvt8(&w_in[(size_t)(n0 + row) * 1024 + k0 + col]);
        }
        __syncthreads();
        short8 af[4], bfr[4];
#pragma unroll
        for (int mt = 0; mt < 4; mt++)
            af[mt] = *(const short8*)&As[(wm0 + mt * 16 + l15) * 40 + quad * 8];
#pragma unroll
        for (int nt = 0; nt < 4; nt++)
            bfr[nt] = *(const short8*)&Bs[(wn0 + nt * 16 + l15) * 40 + quad * 8];
#pragma unroll
        for (int mt = 0; mt < 4; mt++)
#pragma unroll
            for (int nt = 0; nt < 4; nt++)
                acc[mt][nt] = __builtin_amdgcn_mfma_f32_16x16x32_bf16(
                    af[mt], bfr[nt], acc[mt][nt], 0, 0, 0);
    }

    const int plane = n0 >> 10;
    const int dcol0 = n0 & 1023;
    u16* dst = (plane == 0) ? g_buf : ((plane == 1) ? v_buf : f_buf);
#pragma unroll
    for (int mt = 0; mt < 4; mt++) {
#pragma unroll
        for (int r = 0; r < 4; r++) {
            int m = m0 + wm0 + mt * 16 + quad * 4 + r;
#pragma unroll
            for (int nt = 0; nt < 4; nt++) {
                int d = dcol0 + wn0 + nt * 16 + l15;
                float val = acc[mt][nt][r];
                if (plane == 0) val = sigmoidf_(val);
                else if (plane == 2) val = sigmoidf_(val - 1.f);
                dst[(size_t)m * 1024 + d] = f2bf(val);
            }
        }
    }
}

// ---------------- GEMM2: out_pre(bf16) @ w_out^T(fp32) + residual x(fp32) -> out fp32 ----
__global__ __launch_bounds__(256) void gemm2_kernel(const u16* __restrict__ op,
                                                    const float* __restrict__ w_out,
                                                    const float* __restrict__ xres,
                                                    float* __restrict__ out) {
    __shared__ __align__(16) u16 As[128 * 40];
    __shared__ __align__(16) u16 Bs[128 * 40];
    const int m0 = blockIdx.y * 128;
    const int n0 = blockIdx.x * 128;
    const int t = threadIdx.x;
    const int wave = t >> 6, lane = t & 63;
    const int wm0 = (wave >> 1) * 64, wn0 = (wave & 1) * 64;
    const int l15 = lane & 15, quad = lane >> 4;

    floatx4 acc[4][4];
#pragma unroll
    for (int i = 0; i < 4; i++)
#pragma unroll
        for (int j = 0; j < 4; j++) { floatx4 z = {0.f, 0.f, 0.f, 0.f}; acc[i][j] = z; }

    for (int k0 = 0; k0 < 1024; k0 += 32) {
        __syncthreads();
#pragma unroll
        for (int i = 0; i < 2; i++) {
            int c = t + i * 256;
            int row = c >> 2, col = (c & 3) * 8;
            *(short8*)&As[row * 40 + col] =
                *(const short8*)&op[(size_t)(m0 + row) * 1024 + k0 + col];
            *(short8*)&Bs[row * 40 + col] =
                cvt8(&w_out[(size_t)(n0 + row) * 1024 + k0 + col]);
        }
        __syncthreads();
        short8 af[4], bfr[4];
#pragma unroll
        for (int mt = 0; mt < 4; mt++)
            af[mt] = *(const short8*)&As[(wm0 + mt * 16 + l15) * 40 + quad * 8];
#pragma unroll
        for (int nt = 0; nt < 4; nt++)
            bfr[nt] = *(const short8*)&Bs[(wn0 + nt * 16 + l15) * 40 + quad * 8];
#pragma unroll
        for (int mt = 0; mt < 4; mt++)
#pragma unroll
            for (int nt = 0; nt < 4; nt++)
                acc[mt][nt] = __builtin_amdgcn_mfma_f32_16x16x32_bf16(
                    af[mt], bfr[nt], acc[mt][nt], 0, 0, 0);
    }

#pragma unroll
    for (int mt = 0; mt < 4; mt++) {
#pragma unroll
        for (int r = 0; r < 4; r++) {
            int m = m0 + wm0 + mt * 16 + quad * 4 + r;
#pragma unroll
            for (int nt = 0; nt < 4; nt++) {
                int n = n0 + wn0 + nt * 16 + l15;
                size_t idx = (size_t)m * 1024 + n;
                out[idx] = acc[mt][nt][r] + xres[idx];
            }
        }
    }
}

// ---------------- Chunked parallel scan over L ----------------
// Pass 1: per-chunk composed affine map h_end = A*h_in + Bv
__global__ __launch_bounds__(256) void scan1_kernel(const u16* __restrict__ f_buf,
                                                    const u16* __restrict__ v_buf,
                                                    float* __restrict__ Aarr,
                                                    float* __restrict__ Barr) {
    const int wid = blockIdx.x * 4 + (threadIdx.x >> 6);  // 0..8191
    const int lane = threadIdx.x & 63;
    const int b = wid >> 10;
    const int rem = wid & 1023;
    const int c = rem >> 4;
    const int db = (rem & 15) * 64 + lane;
    float A = 1.f, Bv = 0.f;
    size_t base = ((size_t)b * L_ + c * CLEN) * D_ + db;
#pragma unroll 4
    for (int tt = 0; tt < CLEN; tt++) {
        float fv = bf2f(f_buf[base + (size_t)tt * D_]);
        float vv = bf2f(v_buf[base + (size_t)tt * D_]);
        A *= fv;
        Bv = fv * Bv + (1.f - fv) * vv;
    }
    size_t sidx = ((size_t)b * NCHUNK + c) * D_ + db;
    Aarr[sidx] = A;
    Barr[sidx] = Bv;
}

// Pass 2: serial scan across the 64 chunk states per (b,d) channel -> h_in per chunk
__global__ __launch_bounds__(256) void scan2_kernel(const float* __restrict__ Aarr,
                                                    const float* __restrict__ Barr,
                                                    float* __restrict__ hin) {
    const int id = blockIdx.x * 256 + threadIdx.x;  // 0..8191
    const int b = id >> 10, d = id & 1023;
    float h = 0.f;
    for (int c = 0; c < NCHUNK; c++) {
        size_t idx = ((size_t)b * NCHUNK + c) * D_ + d;
        hin[idx] = h;
        h = Aarr[idx] * h + Barr[idx];
    }
}

// Pass 3: replay recurrence from h_in; out_pre = g*h written IN PLACE over the g plane
// (single pointer g_io; each idx read-then-written by the same thread in the same step)
__global__ __launch_bounds__(256) void scan3_kernel(const u16* __restrict__ f_buf,
                                                    const u16* __restrict__ v_buf,
                                                    u16* g_io,
                                                    const float* __restrict__ hin) {
    const int wid = blockIdx.x * 4 + (threadIdx.x >> 6);
    const int lane = threadIdx.x & 63;
    const int b = wid >> 10;
    const int rem = wid & 1023;
    const int c = rem >> 4;
    const int db = (rem & 15) * 64 + lane;
    size_t base = ((size_t)b * L_ + c * CLEN) * D_ + db;
    float h = hin[((size_t)b * NCHUNK + c) * D_ + db];
#pragma unroll 4
    for (int tt = 0; tt < CLEN; tt++) {
        size_t idx = base + (size_t)tt * D_;
        float fv = bf2f(f_buf[idx]);
        float vv = bf2f(v_buf[idx]);
        float gv = bf2f(g_io[idx]);
        h = fv * h + (1.f - fv) * vv;
        g_io[idx] = f2bf(gv * h);
    }
}

extern "C" void kernel_launch(void* const* d_in, const int* in_sizes, int n_in,
                              void* d_out, int out_size, void* d_ws, size_t ws_size,
                              hipStream_t stream) {
    const float* x     = (const float*)d_in[0];  // [8,4096,1024] fp32
    const float* w_in  = (const float*)d_in[1];  // [3072,1024]  fp32
    const float* w_out = (const float*)d_in[2];  // [1024,1024]  fp32
    const float* scale = (const float*)d_in[3];  // [1024]       fp32
    float* out = (float*)d_out;                  // [8,4096,1024] fp32 (128 MiB)

    // d_out doubles as scratch before the final GEMM: two bf16 planes (f, v)
    // exactly fill its 128 MiB; both are dead once gemm2 starts writing fp32.
    u16* f_buf = (u16*)d_out;                        // 64 MiB
    u16* v_buf = (u16*)d_out + (size_t)M_ * D_;      // 64 MiB

    // Workspace: g plane (64 MiB, becomes out_pre) + inv + scan state ~= 70.2 MiB
    char* ws = (char*)d_ws;
    u16* g_buf = (u16*)ws;
    float* inv  = (float*)(ws + (size_t)M_ * D_ * sizeof(u16));
    float* Aarr = inv + M_;                          // [8,64,1024] f32 = 2 MiB
    float* Barr = Aarr + (size_t)B_ * NCHUNK * D_;
    float* hin  = Barr + (size_t)B_ * NCHUNK * D_;

    rmsinv_kernel<<<M_, 256, 0, stream>>>(x, inv);
    gemm1_kernel<<<dim3(3 * D_ / 128, M_ / 128), 256, 0, stream>>>(
        x, inv, scale, w_in, g_buf, v_buf, f_buf);
    scan1_kernel<<<(B_ * NCHUNK * 16) / 4, 256, 0, stream>>>(f_buf, v_buf, Aarr, Barr);
    scan2_kernel<<<(B_ * D_) / 256, 256, 0, stream>>>(Aarr, Barr, hin);
    scan3_kernel<<<(B_ * NCHUNK * 16) / 4, 256, 0, stream>>>(f_buf, v_buf, g_buf, hin);
    gemm2_kernel<<<dim3(D_ / 128, M_ / 128), 256, 0, stream>>>(g_buf, w_out, x, out);
}

// Round 4
// 766.328 us; speedup vs baseline: 1.1792x; 1.1792x over previous
//
#include <hip/hip_runtime.h>
#include <cstdint>
#include <cstddef>

typedef unsigned short u16;
typedef __attribute__((ext_vector_type(8))) short short8;
typedef __attribute__((ext_vector_type(4))) float floatx4;
typedef __attribute__((ext_vector_type(4))) unsigned short ushort4v;

constexpr int D_ = 1024;
constexpr int B_ = 8;
constexpr int L_ = 4096;
constexpr int M_ = B_ * L_;        // 32768 tokens
constexpr int NCHUNK = 64;
constexpr int CLEN = L_ / NCHUNK;  // 64
constexpr float EPS_ = 1e-6f;
constexpr size_t WIN_ELEMS = (size_t)3 * D_ * D_;   // 3145728
constexpr size_t WOUT_ELEMS = (size_t)D_ * D_;      // 1048576

__device__ __forceinline__ float bf2f(u16 b) {
    union { unsigned u; float f; } x; x.u = ((unsigned)b) << 16; return x.f;
}
__device__ __forceinline__ u16 f2bf(float f) {
    union { float f; unsigned u; } x; x.f = f;
    unsigned r = x.u + 0x7fffu + ((x.u >> 16) & 1u);
    return (u16)(r >> 16);
}
__device__ __forceinline__ float sigmoidf_(float x) {
    return 1.f / (1.f + __expf(-x));
}
__device__ __forceinline__ short8 cvt8(const float* __restrict__ p) {
    float4 a = *(const float4*)p;
    float4 b = *(const float4*)(p + 4);
    short8 o;
    o[0] = (short)f2bf(a.x); o[1] = (short)f2bf(a.y);
    o[2] = (short)f2bf(a.z); o[3] = (short)f2bf(a.w);
    o[4] = (short)f2bf(b.x); o[5] = (short)f2bf(b.y);
    o[6] = (short)f2bf(b.z); o[7] = (short)f2bf(b.w);
    return o;
}
// async 16B/lane global->LDS; LDS dest = wave-uniform base + lane*16
__device__ __forceinline__ void gload16(const void* g, void* l) {
    __builtin_amdgcn_global_load_lds((const __attribute__((address_space(1))) void*)g,
                                     (__attribute__((address_space(3))) void*)l, 16, 0, 0);
}

// ---------- prep_xn: fused RMSNorm -> xn = bf16(x * inv * scale), one block/token ----------
__global__ __launch_bounds__(256) void prep_xn_kernel(const float* __restrict__ x,
                                                      const float* __restrict__ scale,
                                                      u16* __restrict__ xn) {
    const int row = blockIdx.x;
    const int t = threadIdx.x;
    const float* xr = x + (size_t)row * D_;
    float4 xv = ((const float4*)xr)[t];
    float ss = xv.x * xv.x + xv.y * xv.y + xv.z * xv.z + xv.w * xv.w;
#pragma unroll
    for (int m = 32; m >= 1; m >>= 1) ss += __shfl_xor(ss, m, 64);
    __shared__ float red[4];
    const int wave = t >> 6, lane = t & 63;
    if (lane == 0) red[wave] = ss;
    __syncthreads();
    float tot = red[0] + red[1] + red[2] + red[3];
    float inv = 1.f / (sqrtf(tot * (1.f / D_)) + EPS_);
    float4 sv = ((const float4*)scale)[t];
    ushort4v o;
    o[0] = f2bf(xv.x * inv * sv.x);
    o[1] = f2bf(xv.y * inv * sv.y);
    o[2] = f2bf(xv.z * inv * sv.z);
    o[3] = f2bf(xv.w * inv * sv.w);
    ((ushort4v*)(xn + (size_t)row * D_))[t] = o;
}

// ---------- prep_w: fp32 -> bf16 for both weight matrices ----------
__global__ __launch_bounds__(256) void prep_w_kernel(const float* __restrict__ w_in,
                                                     const float* __restrict__ w_out,
                                                     u16* __restrict__ w_in_bf,
                                                     u16* __restrict__ w_out_bf) {
    size_t i8 = ((size_t)blockIdx.x * 256 + threadIdx.x) * 8;
    if (i8 < WIN_ELEMS) {
        *(short8*)(w_in_bf + i8) = cvt8(w_in + i8);
    } else {
        size_t j = i8 - WIN_ELEMS;
        *(short8*)(w_out_bf + j) = cvt8(w_out + j);
    }
}

// ---------- m97-style bf16 GEMM core: 128x128 tile, BK=32, global_load_lds w16 ----------
// gA: [*,1024] bf16 row-major; gB: [*,1024] bf16 row-major (weights, B^T layout).
// LDS unpadded [128][32] (64B rows) — required by global_load_lds lane ordering.
__device__ __forceinline__ void gemm_core(const u16* __restrict__ gA,
                                          const u16* __restrict__ gB,
                                          int m0, int n0,
                                          u16* As, u16* Bs,
                                          floatx4 (&acc)[4][4]) {
    const int t = threadIdx.x;
    const int wave = t >> 6, lane = t & 63;
    const int wm0 = (wave >> 1) * 64, wn0 = (wave & 1) * 64;
    const int l15 = lane & 15, quad = lane >> 4;

#pragma unroll
    for (int i = 0; i < 4; i++)
#pragma unroll
        for (int j = 0; j < 4; j++) { floatx4 z = {0.f, 0.f, 0.f, 0.f}; acc[i][j] = z; }

    const int srow = lane >> 2;         // 0..15 within a 16-row block
    const int scol = (lane & 3) * 8;    // element offset (16B chunks)
    const int rb0 = wave * 2;           // each wave stages 2x16 rows of A and of B

    const u16* gA0 = gA + (size_t)(m0 + rb0 * 16 + srow) * 1024 + scol;
    const u16* gB0 = gB + (size_t)(n0 + rb0 * 16 + srow) * 1024 + scol;
    u16* lA0 = As + rb0 * 512;          // 16 rows x 32 cols = 512 elems per block
    u16* lB0 = Bs + rb0 * 512;

    for (int k0 = 0; k0 < 1024; k0 += 32) {
        __syncthreads();                 // previous iter's ds_reads drained
        gload16(gA0 + k0, lA0);
        gload16(gA0 + k0 + 16 * 1024, lA0 + 512);
        gload16(gB0 + k0, lB0);
        gload16(gB0 + k0 + 16 * 1024, lB0 + 512);
        __syncthreads();                 // async loads drained (vmcnt(0) before barrier)
        short8 af[4], bfr[4];
#pragma unroll
        for (int mt = 0; mt < 4; mt++)
            af[mt] = *(const short8*)&As[(wm0 + mt * 16 + l15) * 32 + quad * 8];
#pragma unroll
        for (int nt = 0; nt < 4; nt++)
            bfr[nt] = *(const short8*)&Bs[(wn0 + nt * 16 + l15) * 32 + quad * 8];
#pragma unroll
        for (int mt = 0; mt < 4; mt++)
#pragma unroll
            for (int nt = 0; nt < 4; nt++)
                acc[mt][nt] = __builtin_amdgcn_mfma_f32_16x16x32_bf16(
                    af[mt], bfr[nt], acc[mt][nt], 0, 0, 0);
    }
}

// GEMM1: xn @ w_in^T, fused activations into 3 planes
__global__ __launch_bounds__(256) void gemm1_kernel(const u16* __restrict__ xn,
                                                    const u16* __restrict__ w_in,
                                                    u16* __restrict__ g_buf,
                                                    u16* __restrict__ v_buf,
                                                    u16* __restrict__ f_buf) {
    __shared__ __align__(16) u16 As[128 * 32];
    __shared__ __align__(16) u16 Bs[128 * 32];
    const int m0 = blockIdx.y * 128;
    const int n0 = blockIdx.x * 128;
    floatx4 acc[4][4];
    gemm_core(xn, w_in, m0, n0, As, Bs, acc);

    const int t = threadIdx.x;
    const int wave = t >> 6, lane = t & 63;
    const int wm0 = (wave >> 1) * 64, wn0 = (wave & 1) * 64;
    const int l15 = lane & 15, quad = lane >> 4;
    const int plane = n0 >> 10;
    const int dcol0 = n0 & 1023;
    u16* dst = (plane == 0) ? g_buf : ((plane == 1) ? v_buf : f_buf);
#pragma unroll
    for (int mt = 0; mt < 4; mt++) {
#pragma unroll
        for (int r = 0; r < 4; r++) {
            int m = m0 + wm0 + mt * 16 + quad * 4 + r;
#pragma unroll
            for (int nt = 0; nt < 4; nt++) {
                int d = dcol0 + wn0 + nt * 16 + l15;
                float val = acc[mt][nt][r];
                if (plane == 0) val = sigmoidf_(val);
                else if (plane == 2) val = sigmoidf_(val - 1.f);
                dst[(size_t)m * 1024 + d] = f2bf(val);
            }
        }
    }
}

// GEMM2: out_pre(bf16) @ w_out_bf^T + residual x(fp32) -> out fp32
__global__ __launch_bounds__(256) void gemm2_kernel(const u16* __restrict__ op,
                                                    const u16* __restrict__ w_out,
                                                    const float* __restrict__ xres,
                                                    float* __restrict__ out) {
    __shared__ __align__(16) u16 As[128 * 32];
    __shared__ __align__(16) u16 Bs[128 * 32];
    const int m0 = blockIdx.y * 128;
    const int n0 = blockIdx.x * 128;
    floatx4 acc[4][4];
    gemm_core(op, w_out, m0, n0, As, Bs, acc);

    const int t = threadIdx.x;
    const int wave = t >> 6, lane = t & 63;
    const int wm0 = (wave >> 1) * 64, wn0 = (wave & 1) * 64;
    const int l15 = lane & 15, quad = lane >> 4;
#pragma unroll
    for (int mt = 0; mt < 4; mt++) {
#pragma unroll
        for (int r = 0; r < 4; r++) {
            int m = m0 + wm0 + mt * 16 + quad * 4 + r;
#pragma unroll
            for (int nt = 0; nt < 4; nt++) {
                int n = n0 + wn0 + nt * 16 + l15;
                size_t idx = (size_t)m * 1024 + n;
                out[idx] = acc[mt][nt][r] + xres[idx];
            }
        }
    }
}

// ---------------- Chunked parallel scan over L (3 passes) ----------------
__global__ __launch_bounds__(256) void scan1_kernel(const u16* __restrict__ f_buf,
                                                    const u16* __restrict__ v_buf,
                                                    float* __restrict__ Aarr,
                                                    float* __restrict__ Barr) {
    const int wid = blockIdx.x * 4 + (threadIdx.x >> 6);  // 0..8191
    const int lane = threadIdx.x & 63;
    const int b = wid >> 10;
    const int rem = wid & 1023;
    const int c = rem >> 4;
    const int db = (rem & 15) * 64 + lane;
    float A = 1.f, Bv = 0.f;
    size_t base = ((size_t)b * L_ + c * CLEN) * D_ + db;
#pragma unroll 4
    for (int tt = 0; tt < CLEN; tt++) {
        float fv = bf2f(f_buf[base + (size_t)tt * D_]);
        float vv = bf2f(v_buf[base + (size_t)tt * D_]);
        A *= fv;
        Bv = fv * Bv + (1.f - fv) * vv;
    }
    size_t sidx = ((size_t)b * NCHUNK + c) * D_ + db;
    Aarr[sidx] = A;
    Barr[sidx] = Bv;
}

__global__ __launch_bounds__(256) void scan2_kernel(const float* __restrict__ Aarr,
                                                    const float* __restrict__ Barr,
                                                    float* __restrict__ hin) {
    const int id = blockIdx.x * 256 + threadIdx.x;  // 0..8191
    const int b = id >> 10, d = id & 1023;
    float h = 0.f;
    for (int c = 0; c < NCHUNK; c++) {
        size_t idx = ((size_t)b * NCHUNK + c) * D_ + d;
        hin[idx] = h;
        h = Aarr[idx] * h + Barr[idx];
    }
}

__global__ __launch_bounds__(256) void scan3_kernel(const u16* __restrict__ f_buf,
                                                    const u16* __restrict__ v_buf,
                                                    u16* g_io,
                                                    const float* __restrict__ hin) {
    const int wid = blockIdx.x * 4 + (threadIdx.x >> 6);
    const int lane = threadIdx.x & 63;
    const int b = wid >> 10;
    const int rem = wid & 1023;
    const int c = rem >> 4;
    const int db = (rem & 15) * 64 + lane;
    size_t base = ((size_t)b * L_ + c * CLEN) * D_ + db;
    float h = hin[((size_t)b * NCHUNK + c) * D_ + db];
#pragma unroll 4
    for (int tt = 0; tt < CLEN; tt++) {
        size_t idx = base + (size_t)tt * D_;
        float fv = bf2f(f_buf[idx]);
        float vv = bf2f(v_buf[idx]);
        float gv = bf2f(g_io[idx]);
        h = fv * h + (1.f - fv) * vv;
        g_io[idx] = f2bf(gv * h);
    }
}

extern "C" void kernel_launch(void* const* d_in, const int* in_sizes, int n_in,
                              void* d_out, int out_size, void* d_ws, size_t ws_size,
                              hipStream_t stream) {
    const float* x     = (const float*)d_in[0];  // [8,4096,1024] fp32
    const float* w_in  = (const float*)d_in[1];  // [3072,1024]  fp32
    const float* w_out = (const float*)d_in[2];  // [1024,1024]  fp32
    const float* scale = (const float*)d_in[3];  // [1024]       fp32
    float* out = (float*)d_out;                  // [8,4096,1024] fp32 (128 MiB)

    // d_out doubles as scratch before the final GEMM: f and v bf16 planes.
    u16* f_buf = (u16*)d_out;                        // 64 MiB
    u16* v_buf = (u16*)d_out + (size_t)M_ * D_;      // 64 MiB

    // Workspace (~142 MiB): xn(64) + g(64) + w_in_bf(6) + w_out_bf(2) + scan(6)
    char* ws = (char*)d_ws;
    const size_t PLANE = (size_t)M_ * D_ * sizeof(u16);  // 64 MiB
    u16* xn    = (u16*)ws;
    u16* g_buf = (u16*)(ws + PLANE);
    u16* w_in_bf  = (u16*)(ws + 2 * PLANE);
    u16* w_out_bf = w_in_bf + WIN_ELEMS;
    float* Aarr = (float*)(ws + 2 * PLANE + (WIN_ELEMS + WOUT_ELEMS) * sizeof(u16));
    float* Barr = Aarr + (size_t)B_ * NCHUNK * D_;
    float* hin  = Barr + (size_t)B_ * NCHUNK * D_;

    prep_xn_kernel<<<M_, 256, 0, stream>>>(x, scale, xn);
    prep_w_kernel<<<(int)((WIN_ELEMS + WOUT_ELEMS) / 8 / 256), 256, 0, stream>>>(
        w_in, w_out, w_in_bf, w_out_bf);
    gemm1_kernel<<<dim3(3 * D_ / 128, M_ / 128), 256, 0, stream>>>(
        xn, w_in_bf, g_buf, v_buf, f_buf);
    scan1_kernel<<<(B_ * NCHUNK * 16) / 4, 256, 0, stream>>>(f_buf, v_buf, Aarr, Barr);
    scan2_kernel<<<(B_ * D_) / 256, 256, 0, stream>>>(Aarr, Barr, hin);
    scan3_kernel<<<(B_ * NCHUNK * 16) / 4, 256, 0, stream>>>(f_buf, v_buf, g_buf, hin);
    gemm2_kernel<<<dim3(D_ / 128, M_ / 128), 256, 0, stream>>>(g_buf, w_out_bf, x, out);
}